// Round 1
// baseline (1254.026 us; speedup 1.0000x reference)
//
#include <hip/hip_runtime.h>
#include <cstddef>
#include <cstdint>

#define BN_EPS 1e-5f

__device__ __forceinline__ float4 fma4(float s, float4 v, float4 a) {
  a.x = fmaf(s, v.x, a.x);
  a.y = fmaf(s, v.y, a.y);
  a.z = fmaf(s, v.z, a.z);
  a.w = fmaf(s, v.w, a.w);
  return a;
}

// ---------------------------------------------------------------------------
// K1: BatchNorm (eval). x[4,256,128,128] -> xb. One thread per float4.
__global__ __launch_bounds__(256) void bn_kernel(
    const float* __restrict__ x, const float* __restrict__ gamma,
    const float* __restrict__ beta, const float* __restrict__ mean,
    const float* __restrict__ var, float* __restrict__ xb) {
  size_t i = (size_t)blockIdx.x * 256 + threadIdx.x;  // float4 index
  int c = (int)((i >> 12) & 255);                     // 4096 f4 per plane
  float s = gamma[c] * rsqrtf(var[c] + BN_EPS);
  float sh = beta[c] - mean[c] * s;
  float4 v = reinterpret_cast<const float4*>(x)[i];
  v.x = fmaf(v.x, s, sh);
  v.y = fmaf(v.y, s, sh);
  v.z = fmaf(v.z, s, sh);
  v.w = fmaf(v.w, s, sh);
  reinterpret_cast<float4*>(xb)[i] = v;
}

// ---------------------------------------------------------------------------
// K2: depthwise 3x3, pad 1, on [4,256,128,128]. One thread per 4 output cols.
// grid: (b*256+c)*16 + rowgroup ; block 256 = 8 rows x 32 col4
__global__ __launch_bounds__(256) void dw_kernel(
    const float* __restrict__ in, const float* __restrict__ wall,
    float* __restrict__ out) {
  int blk = blockIdx.x;
  int sub = blk & 15;
  int bc = blk >> 4;  // b*256+c
  int c = bc & 255;
  int row = sub * 8 + (threadIdx.x >> 5);
  int col4 = threadIdx.x & 31;
  const float* w = wall + c * 9;
  const float* base = in + (size_t)bc * 16384;
  float4 acc = make_float4(0.f, 0.f, 0.f, 0.f);
#pragma unroll
  for (int dr = -1; dr <= 1; dr++) {
    int rr = row + dr;
    if (rr < 0 || rr > 127) continue;
    const float* rp = base + rr * 128;
    float4 v = reinterpret_cast<const float4*>(rp)[col4];
    float lf = col4 ? rp[col4 * 4 - 1] : 0.f;
    float rg = (col4 < 31) ? rp[col4 * 4 + 4] : 0.f;
    float k0 = w[(dr + 1) * 3 + 0];
    float k1 = w[(dr + 1) * 3 + 1];
    float k2 = w[(dr + 1) * 3 + 2];
    acc.x = fmaf(k0, lf, fmaf(k1, v.x, fmaf(k2, v.y, acc.x)));
    acc.y = fmaf(k0, v.x, fmaf(k1, v.y, fmaf(k2, v.z, acc.y)));
    acc.z = fmaf(k0, v.y, fmaf(k1, v.z, fmaf(k2, v.w, acc.z)));
    acc.w = fmaf(k0, v.z, fmaf(k1, v.w, fmaf(k2, rg, acc.w)));
  }
  reinterpret_cast<float4*>(out + (size_t)bc * 16384 + row * 128)[col4] = acc;
}

// ---------------------------------------------------------------------------
// K3: 1x1 conv (256->256) over full res, fused 4x4 maxpool + activation.
// act: 0 = sigmoid, 1 = relu. Block computes 32 oc x (4 rows x 128 cols),
// writes 32 oc x 32 pooled outputs. grid (32 pooled rows, 8 oc tiles, 4 b).
__global__ __launch_bounds__(256) void pw_pool_kernel(
    const float* __restrict__ in, const float* __restrict__ W,
    float* __restrict__ out, int act) {
  __shared__ float in_t[16 * 512];
  __shared__ float w_t[16 * 32];
  const int tid = threadIdx.x;
  const int prow = blockIdx.x;
  const int oc0 = blockIdx.y * 32;
  const int b = blockIdx.z;
  const int og = tid >> 5;  // 0..7 -> 4 oc each
  const int pp = tid & 31;  // pooled col = 4 full cols

  float4 acc[4][4];
#pragma unroll
  for (int o = 0; o < 4; o++)
#pragma unroll
    for (int r = 0; r < 4; r++) acc[o][r] = make_float4(0.f, 0.f, 0.f, 0.f);

  const float4* in4 = reinterpret_cast<const float4*>(in);
  float4* in_t4 = reinterpret_cast<float4*>(in_t);

  for (int c0 = 0; c0 < 256; c0 += 16) {
#pragma unroll
    for (int k = 0; k < 8; k++) {
      int flat = k * 256 + tid;  // = c*128 + rem
      int cc = flat >> 7;
      int rem = flat & 127;  // r*32 + col4
      in_t4[flat] =
          in4[(size_t)(b * 256 + c0 + cc) * 4096 + (size_t)prow * 128 + rem];
    }
#pragma unroll
    for (int k = 0; k < 2; k++) {
      int flat = k * 256 + tid;
      int cc = flat & 15;
      int oc = flat >> 4;
      w_t[cc * 32 + oc] = W[(size_t)(oc0 + oc) * 256 + c0 + cc];
    }
    __syncthreads();
#pragma unroll
    for (int cc = 0; cc < 16; cc++) {
      float4 w4 = reinterpret_cast<const float4*>(w_t)[cc * 8 + og];
      const float4* rowp = in_t4 + cc * 128;
      float4 v0 = rowp[pp];
      float4 v1 = rowp[32 + pp];
      float4 v2 = rowp[64 + pp];
      float4 v3 = rowp[96 + pp];
      acc[0][0] = fma4(w4.x, v0, acc[0][0]);
      acc[0][1] = fma4(w4.x, v1, acc[0][1]);
      acc[0][2] = fma4(w4.x, v2, acc[0][2]);
      acc[0][3] = fma4(w4.x, v3, acc[0][3]);
      acc[1][0] = fma4(w4.y, v0, acc[1][0]);
      acc[1][1] = fma4(w4.y, v1, acc[1][1]);
      acc[1][2] = fma4(w4.y, v2, acc[1][2]);
      acc[1][3] = fma4(w4.y, v3, acc[1][3]);
      acc[2][0] = fma4(w4.z, v0, acc[2][0]);
      acc[2][1] = fma4(w4.z, v1, acc[2][1]);
      acc[2][2] = fma4(w4.z, v2, acc[2][2]);
      acc[2][3] = fma4(w4.z, v3, acc[2][3]);
      acc[3][0] = fma4(w4.w, v0, acc[3][0]);
      acc[3][1] = fma4(w4.w, v1, acc[3][1]);
      acc[3][2] = fma4(w4.w, v2, acc[3][2]);
      acc[3][3] = fma4(w4.w, v3, acc[3][3]);
    }
    __syncthreads();
  }
#pragma unroll
  for (int o = 0; o < 4; o++) {
    float m = -3.4e38f;
#pragma unroll
    for (int r = 0; r < 4; r++) {
      float4 a_ = acc[o][r];
      m = fmaxf(m, fmaxf(fmaxf(a_.x, a_.y), fmaxf(a_.z, a_.w)));
    }
    float zv = act ? fmaxf(m, 0.f) : 1.f / (1.f + expf(-m));
    out[(size_t)(b * 256 + oc0 + og * 4 + o) * 1024 + prow * 32 + pp] = zv;
  }
}

// ---------------------------------------------------------------------------
// K4: avgpool grads, build grid_sample coefficients for grid1/grid2.
__device__ __forceinline__ void make_samp(float sx, float sy, int4* oi,
                                          float4* ow) {
  float x0f = floorf(sx), y0f = floorf(sy);
  float wx = sx - x0f, wy = sy - y0f;
  int x0 = (int)x0f, y0 = (int)y0f;
  bool vx0 = (x0f >= 0.f) && (x0f <= 31.f);
  bool vx1 = (x0f + 1.f >= 0.f) && (x0f + 1.f <= 31.f);
  bool vy0 = (y0f >= 0.f) && (y0f <= 31.f);
  bool vy1 = (y0f + 1.f >= 0.f) && (y0f + 1.f <= 31.f);
  int x0c = min(max(x0, 0), 31), x1c = min(max(x0 + 1, 0), 31);
  int y0c = min(max(y0, 0), 31), y1c = min(max(y0 + 1, 0), 31);
  *oi = make_int4(x0c, x1c, y0c, y1c);
  *ow = make_float4((1.f - wx) * (1.f - wy) * ((vx0 && vy0) ? 1.f : 0.f),
                    wx * (1.f - wy) * ((vx1 && vy0) ? 1.f : 0.f),
                    (1.f - wx) * wy * ((vx0 && vy1) ? 1.f : 0.f),
                    wx * wy * ((vx1 && vy1) ? 1.f : 0.f));
}

__global__ void grads_pool_kernel(const float* __restrict__ grads,
                                  int4* __restrict__ s1i,
                                  float4* __restrict__ s1w,
                                  int4* __restrict__ s2i,
                                  float4* __restrict__ s2w) {
  unsigned flat = blockIdx.x * 256u + threadIdx.x;  // 0..4095
  unsigned pw = flat & 31u, ph = (flat >> 5) & 31u, b = flat >> 10;
  const float* gx = grads + (size_t)(b * 2 + 0) * 16384;
  const float* gy = grads + (size_t)(b * 2 + 1) * 16384;
  float sx_ = 0.f, sy_ = 0.f;
#pragma unroll
  for (int r = 0; r < 4; r++) {
    const float* rx = gx + (ph * 4 + r) * 128 + pw * 4;
    const float* ry = gy + (ph * 4 + r) * 128 + pw * 4;
#pragma unroll
    for (int q = 0; q < 4; q++) {
      sx_ += rx[q];
      sy_ += ry[q];
    }
  }
  float gxa = sx_ * (1.f / 16.f) * (1.f / 32.f);
  float gya = sy_ * (1.f / 16.f) * (1.f / 32.f);
  float basex = -1.f + pw * (2.f / 31.f);
  float basey = -1.f + ph * (2.f / 31.f);
  unsigned sidx = b * 1024u + ph * 32u + pw;
  {
    float sx = (basex + gxa + 1.f) * 15.5f;
    float sy = (basey + gya + 1.f) * 15.5f;
    make_samp(sx, sy, &s1i[sidx], &s1w[sidx]);
  }
  {
    float sx = (basex - gxa + 1.f) * 15.5f;
    float sy = (basey - gya + 1.f) * 15.5f;
    make_samp(sx, sy, &s2i[sidx], &s2w[sidx]);
  }
}

// ---------------------------------------------------------------------------
// K5: m = grid_sample(m_prev) * a, both branches in one launch.
__global__ __launch_bounds__(256) void gs_mul_kernel(
    const float* __restrict__ in0, const float* __restrict__ am0,
    const int4* __restrict__ si0, const float4* __restrict__ sw0,
    float* __restrict__ o0, const float* __restrict__ in1,
    const float* __restrict__ am1, const int4* __restrict__ si1,
    const float4* __restrict__ sw1, float* __restrict__ o1) {
  unsigned flat = blockIdx.x * 256u + threadIdx.x;
  unsigned px = flat & 1023u;
  unsigned c = (flat >> 10) & 255u;
  unsigned b = (flat >> 18) & 3u;
  unsigned br = flat >> 20;
  const float* in = br ? in1 : in0;
  const float* am = br ? am1 : am0;
  const int4* si = br ? si1 : si0;
  const float4* sw = br ? sw1 : sw0;
  float* o = br ? o1 : o0;
  unsigned sidx = b * 1024u + px;
  int4 id = si[sidx];
  float4 w = sw[sidx];
  const float* pl = in + (size_t)(b * 256 + c) * 1024;
  float v = w.x * pl[id.z * 32 + id.x] + w.y * pl[id.z * 32 + id.y] +
            w.z * pl[id.w * 32 + id.x] + w.w * pl[id.w * 32 + id.y];
  size_t oi = (size_t)(b * 256 + c) * 1024 + px;
  o[oi] = v * am[oi];
}

// ---------------------------------------------------------------------------
// K6: 1x1 conv over concat(A,B) channels (512 -> 256) at 32x32.
// Used for the loop's add-convs (both branches via z) and the merge pw.
// cpbA/cpbB: channels-per-batch stride of the A/B tensors.
__global__ __launch_bounds__(256) void conv_cat_kernel(
    const float* __restrict__ inA0, const float* __restrict__ inB0,
    const float* __restrict__ W0, float* __restrict__ out0,
    const float* __restrict__ inA1, const float* __restrict__ inB1,
    const float* __restrict__ W1, float* __restrict__ out1, int cpbA,
    int cpbB) {
  __shared__ float in_t[16 * 128];
  __shared__ float w_t[16 * 32];
  const int tid = threadIdx.x;
  const int pxt = blockIdx.x;  // 0..7 -> 128 px
  const int oc0 = blockIdx.y * 32;
  const int z = blockIdx.z;
  const int b = z & 3;
  const int br = z >> 2;
  const float* inA = br ? inA1 : inA0;
  const float* inB = br ? inB1 : inB0;
  const float* W = br ? W1 : W0;
  float* out = br ? out1 : out0;
  const int og = tid >> 5;
  const int pp = tid & 31;
  float4 acc[4];
#pragma unroll
  for (int o = 0; o < 4; o++) acc[o] = make_float4(0.f, 0.f, 0.f, 0.f);
  float4* in_t4 = reinterpret_cast<float4*>(in_t);
  for (int c0 = 0; c0 < 512; c0 += 16) {
    const float* src = (c0 < 256) ? inA : inB;
    int cpb = (c0 < 256) ? cpbA : cpbB;
    int cb = (c0 < 256) ? c0 : c0 - 256;
#pragma unroll
    for (int k = 0; k < 2; k++) {
      int flat = k * 256 + tid;  // = c*32 + px4
      int cc = flat >> 5;
      int px4 = flat & 31;
      in_t4[flat] = reinterpret_cast<const float4*>(
          src)[(size_t)(b * cpb + cb + cc) * 256 + pxt * 32 + px4];
    }
#pragma unroll
    for (int k = 0; k < 2; k++) {
      int flat = k * 256 + tid;
      int cc = flat & 15;
      int oc = flat >> 4;
      w_t[cc * 32 + oc] = W[(size_t)(oc0 + oc) * 512 + c0 + cc];
    }
    __syncthreads();
#pragma unroll
    for (int cc = 0; cc < 16; cc++) {
      float4 w4 = reinterpret_cast<const float4*>(w_t)[cc * 8 + og];
      float4 v = in_t4[cc * 32 + pp];
      acc[0] = fma4(w4.x, v, acc[0]);
      acc[1] = fma4(w4.y, v, acc[1]);
      acc[2] = fma4(w4.z, v, acc[2]);
      acc[3] = fma4(w4.w, v, acc[3]);
    }
    __syncthreads();
  }
#pragma unroll
  for (int o = 0; o < 4; o++)
    reinterpret_cast<float4*>(
        out)[(size_t)(b * 256 + oc0 + og * 4 + o) * 256 + pxt * 32 + pp] =
        acc[o];
}

// ---------------------------------------------------------------------------
// K7: merge depthwise 3x3 on concat(ms1, ms2)/ITERS -> dwm [4,512,32,32]
__global__ void merge_dw_kernel(const float* __restrict__ s1,
                                const float* __restrict__ s2,
                                const float* __restrict__ wall,
                                float* __restrict__ out) {
  unsigned flat = blockIdx.x * 256u + threadIdx.x;  // 2M
  unsigned px = flat & 1023u;
  unsigned pr = px >> 5, pc = px & 31u;
  unsigned c = (flat >> 10) & 511u;
  unsigned b = flat >> 19;
  const float* pl = (c < 256) ? (s1 + (size_t)(b * 256 + c) * 1024)
                              : (s2 + (size_t)(b * 256 + (c - 256)) * 1024);
  const float* w = wall + c * 9;
  float acc = 0.f;
#pragma unroll
  for (int dr = -1; dr <= 1; dr++) {
    int rr = (int)pr + dr;
    if (rr < 0 || rr > 31) continue;
#pragma unroll
    for (int dc = -1; dc <= 1; dc++) {
      int cc = (int)pc + dc;
      if (cc < 0 || cc > 31) continue;
      acc = fmaf(w[(dr + 1) * 3 + (dc + 1)], pl[rr * 32 + cc], acc);
    }
  }
  out[(size_t)(b * 512 + c) * 1024 + px] = acc * 0.1f;  // 1/ITERS
}

// ---------------------------------------------------------------------------
// K8: bilinear upsample 32->128, align_corners=True. One thread per float4.
__global__ __launch_bounds__(256) void upsample_kernel(
    const float* __restrict__ mid, float* __restrict__ out) {
  unsigned flat = blockIdx.x * 256u + threadIdx.x;  // f4 units
  unsigned ow4 = flat & 31u;
  unsigned oh = (flat >> 5) & 127u;
  unsigned bc = flat >> 12;  // b*256+c
  const float* pl = mid + (size_t)bc * 1024;
  float rh = oh * (31.f / 127.f);
  float ihf = floorf(rh);
  float wh = rh - ihf;
  int i0 = (int)ihf;
  int i1 = min(i0 + 1, 31);
  const float* r0 = pl + i0 * 32;
  const float* r1 = pl + i1 * 32;
  float4 res;
  float* rp = &res.x;
#pragma unroll
  for (int j = 0; j < 4; j++) {
    unsigned ow = ow4 * 4 + j;
    float rw = ow * (31.f / 127.f);
    float jwf = floorf(rw);
    float ww = rw - jwf;
    int j0 = (int)jwf;
    int j1 = min(j0 + 1, 31);
    float top = r0[j0] * (1.f - ww) + r0[j1] * ww;
    float bot = r1[j0] * (1.f - ww) + r1[j1] * ww;
    rp[j] = top * (1.f - wh) + bot * wh;
  }
  reinterpret_cast<float4*>(out)[flat] = res;
}

// ---------------------------------------------------------------------------
extern "C" void kernel_launch(void* const* d_in, const int* in_sizes, int n_in,
                              void* d_out, int out_size, void* d_ws,
                              size_t ws_size, hipStream_t stream) {
  (void)in_sizes;
  (void)n_in;
  (void)out_size;
  (void)ws_size;
  const float* x = (const float*)d_in[0];
  const float* grads = (const float*)d_in[1];
  const float* bn_gamma = (const float*)d_in[2];
  const float* bn_beta = (const float*)d_in[3];
  const float* bn_mean = (const float*)d_in[4];
  const float* bn_var = (const float*)d_in[5];
  const float* att1_dw = (const float*)d_in[6];
  const float* att1_pw = (const float*)d_in[7];
  const float* att2_dw = (const float*)d_in[8];
  const float* att2_pw = (const float*)d_in[9];
  const float* conv1_w = (const float*)d_in[10];
  const float* conv2_w = (const float*)d_in[11];
  const float* add1_w = (const float*)d_in[12];
  const float* add2_w = (const float*)d_in[13];
  const float* merge_dww = (const float*)d_in[14];
  const float* merge_pww = (const float*)d_in[15];
  float* out = (float*)d_out;

  const size_t NFULL = 16777216;  // 4*256*128*128
  const size_t NPOOL = 1048576;   // 4*256*32*32
  const size_t NP2 = 2097152;     // 4*512*32*32
  float* ws = (float*)d_ws;
  float* xb = ws;                 // 64 MB, dead after pw_pool launches
  float* t = ws + NFULL;          // 64 MB, depthwise scratch
  float* a1p = ws + 2 * NFULL;    // pooled tensors live to the end
  float* a2p = a1p + NPOOL;
  float* m1p = a2p + NPOOL;
  float* m2p = m1p + NPOOL;
  float* sampbase = m2p + NPOOL;  // 4 * 4096 * 4 floats
  int4* s1i = (int4*)sampbase;
  float4* s1w = (float4*)(sampbase + 4096 * 4);
  int4* s2i = (int4*)(sampbase + 4096 * 8);
  float4* s2w = (float4*)(sampbase + 4096 * 12);
  // loop region reuses the xb area (44 MB < 64 MB)
  float* lb = ws;
  float* ms1a = lb;
  float* ms1b = lb + NPOOL;
  float* ms2a = lb + 2 * NPOOL;
  float* ms2b = lb + 3 * NPOOL;
  float* mc1a = lb + 4 * NPOOL;
  float* mc1b = lb + 5 * NPOOL;
  float* mc2a = lb + 6 * NPOOL;
  float* mc2b = lb + 7 * NPOOL;
  float* dwm = lb + 8 * NPOOL;          // NP2
  float* out32 = lb + 8 * NPOOL + NP2;  // NPOOL

  bn_kernel<<<16384, 256, 0, stream>>>(x, bn_gamma, bn_beta, bn_mean, bn_var,
                                       xb);
  dw_kernel<<<16384, 256, 0, stream>>>(xb, att1_dw, t);
  pw_pool_kernel<<<dim3(32, 8, 4), 256, 0, stream>>>(t, att1_pw, a1p, 0);
  dw_kernel<<<16384, 256, 0, stream>>>(xb, att2_dw, t);
  pw_pool_kernel<<<dim3(32, 8, 4), 256, 0, stream>>>(t, att2_pw, a2p, 0);
  pw_pool_kernel<<<dim3(32, 8, 4), 256, 0, stream>>>(xb, conv1_w, m1p, 1);
  pw_pool_kernel<<<dim3(32, 8, 4), 256, 0, stream>>>(xb, conv2_w, m2p, 1);
  grads_pool_kernel<<<16, 256, 0, stream>>>(grads, s1i, s1w, s2i, s2w);

  const float* cur1 = m1p;
  const float* sum1 = m1p;
  const float* cur2 = m2p;
  const float* sum2 = m2p;
  float* c1b[2] = {mc1a, mc1b};
  float* c2b[2] = {mc2a, mc2b};
  float* s1b[2] = {ms1a, ms1b};
  float* s2b[2] = {ms2a, ms2b};
  for (int it = 0; it < 10; it++) {
    float* nc1 = c1b[it & 1];
    float* nc2 = c2b[it & 1];
    gs_mul_kernel<<<8192, 256, 0, stream>>>(cur1, a1p, s1i, s1w, nc1, cur2,
                                            a2p, s2i, s2w, nc2);
    float* ns1 = s1b[it & 1];
    float* ns2 = s2b[it & 1];
    conv_cat_kernel<<<dim3(8, 8, 8), 256, 0, stream>>>(
        sum1, nc1, add1_w, ns1, sum2, nc2, add2_w, ns2, 256, 256);
    cur1 = nc1;
    cur2 = nc2;
    sum1 = ns1;
    sum2 = ns2;
  }
  merge_dw_kernel<<<8192, 256, 0, stream>>>(sum1, sum2, merge_dww, dwm);
  conv_cat_kernel<<<dim3(8, 8, 4), 256, 0, stream>>>(
      dwm, dwm + 256 * 1024, merge_pww, out32, nullptr, nullptr, nullptr,
      nullptr, 512, 512);
  upsample_kernel<<<16384, 256, 0, stream>>>(out32, out);
}

// Round 3
// 704.312 us; speedup vs baseline: 1.7805x; 1.7805x over previous
//
#include <hip/hip_runtime.h>
#include <cstddef>
#include <cstdint>

#define BN_EPS 1e-5f
typedef unsigned short ushort_t;
typedef __attribute__((ext_vector_type(8))) short bf16x8;
typedef __attribute__((ext_vector_type(4))) float f32x4;

__device__ __forceinline__ ushort_t f2bf(float f) {
  unsigned u = __float_as_uint(f);
  unsigned r = (u + 0x7fffu + ((u >> 16) & 1u)) >> 16;
  return (ushort_t)r;
}
__device__ __forceinline__ float bf2f(ushort_t h) {
  return __uint_as_float(((unsigned)h) << 16);
}
__device__ __forceinline__ void unp8(uint4 u, ushort_t* d) {
  d[0] = u.x & 0xffff; d[1] = u.x >> 16;
  d[2] = u.y & 0xffff; d[3] = u.y >> 16;
  d[4] = u.z & 0xffff; d[5] = u.z >> 16;
  d[6] = u.w & 0xffff; d[7] = u.w >> 16;
}
__device__ __forceinline__ uint4 pk8(const ushort_t* d) {
  uint4 u;
  u.x = (unsigned)d[0] | ((unsigned)d[1] << 16);
  u.y = (unsigned)d[2] | ((unsigned)d[3] << 16);
  u.z = (unsigned)d[4] | ((unsigned)d[5] << 16);
  u.w = (unsigned)d[6] | ((unsigned)d[7] << 16);
  return u;
}

// ---------------------------------------------------------------------------
// Weight split: fp32 [256][K] -> bf16 [256][2K] = [hi(K) | lo(K)].
// 4 weights with K=256 (rows 0..1023), 3 with K=512 (rows 1024..1791).
__global__ __launch_bounds__(256) void wsplit_kernel(
    const float* s0, const float* s1, const float* s2, const float* s3,
    const float* s4, const float* s5, const float* s6, ushort_t* d0,
    ushort_t* d1, ushort_t* d2, ushort_t* d3, ushort_t* d4, ushort_t* d5,
    ushort_t* d6) {
  int r = blockIdx.x;
  int tid = threadIdx.x;
  if (r < 1024) {
    int wi = r >> 8, oc = r & 255;
    const float* s = wi == 0 ? s0 : wi == 1 ? s1 : wi == 2 ? s2 : s3;
    ushort_t* d = wi == 0 ? d0 : wi == 1 ? d1 : wi == 2 ? d2 : d3;
    float v = s[oc * 256 + tid];
    ushort_t h = f2bf(v);
    d[oc * 512 + tid] = h;
    d[oc * 512 + 256 + tid] = f2bf(v - bf2f(h));
  } else {
    int rr = r - 1024;
    int wi = rr >> 8, oc = rr & 255;
    const float* s = wi == 0 ? s4 : wi == 1 ? s5 : s6;
    ushort_t* d = wi == 0 ? d4 : wi == 1 ? d5 : d6;
#pragma unroll
    for (int p = 0; p < 2; ++p) {
      int k = p * 256 + tid;
      float v = s[oc * 512 + k];
      ushort_t h = f2bf(v);
      d[oc * 1024 + k] = h;
      d[oc * 1024 + 512 + k] = f2bf(v - bf2f(h));
    }
  }
}

// ---------------------------------------------------------------------------
// Depthwise 3x3 pad1 with BN folded into input loads (single branch).
__global__ __launch_bounds__(256) void dw_bn_kernel(
    const float* __restrict__ x, const float* __restrict__ wall,
    const float* __restrict__ gamma, const float* __restrict__ beta,
    const float* __restrict__ mean, const float* __restrict__ var,
    float* __restrict__ out) {
  int blk = blockIdx.x;
  int sub = blk & 15;
  int bc = blk >> 4;  // b*256+c
  int c = bc & 255;
  float s = gamma[c] * rsqrtf(var[c] + BN_EPS);
  float sh = beta[c] - mean[c] * s;
  int row = sub * 8 + (threadIdx.x >> 5);
  int col4 = threadIdx.x & 31;
  const float* w = wall + c * 9;
  const float* base = x + (size_t)bc * 16384;
  float4 acc = make_float4(0.f, 0.f, 0.f, 0.f);
#pragma unroll
  for (int dr = -1; dr <= 1; dr++) {
    int rr = row + dr;
    if (rr < 0 || rr > 127) continue;
    const float* rp = base + rr * 128;
    float4 v = reinterpret_cast<const float4*>(rp)[col4];
    v.x = fmaf(v.x, s, sh);
    v.y = fmaf(v.y, s, sh);
    v.z = fmaf(v.z, s, sh);
    v.w = fmaf(v.w, s, sh);
    float lf = col4 ? fmaf(rp[col4 * 4 - 1], s, sh) : 0.f;
    float rg = (col4 < 31) ? fmaf(rp[col4 * 4 + 4], s, sh) : 0.f;
    float k0 = w[(dr + 1) * 3 + 0];
    float k1 = w[(dr + 1) * 3 + 1];
    float k2 = w[(dr + 1) * 3 + 2];
    acc.x = fmaf(k0, lf, fmaf(k1, v.x, fmaf(k2, v.y, acc.x)));
    acc.y = fmaf(k0, v.x, fmaf(k1, v.y, fmaf(k2, v.z, acc.y)));
    acc.z = fmaf(k0, v.y, fmaf(k1, v.z, fmaf(k2, v.w, acc.z)));
    acc.w = fmaf(k0, v.z, fmaf(k1, v.w, fmaf(k2, rg, acc.w)));
  }
  reinterpret_cast<float4*>(out + (size_t)bc * 16384 + row * 128)[col4] = acc;
}

// ---------------------------------------------------------------------------
// MFMA 1x1 conv (256ic->256oc, bf16x3 split) over full res, fused 4x4
// maxpool + activation. Block = 64 px (4 pool cells) x 256 oc, 4 waves.
// GEMM M = px, with m = c4*16 + r*4 + q so each 16-row M-tile is one 4x4
// pool cell -> pool = in-reg max + shfl_xor 16/32.
// Hi and lo staged together: X read from global ONCE, 3 MFMA terms issued.
// grid (256 strips = pr*8+pcs, 4 b, z branches). Out pooled [b][1024][256].
__global__ __launch_bounds__(256) void pw_mfma_kernel(
    const float* __restrict__ src0, const float* __restrict__ src1,
    const ushort_t* __restrict__ W0, const ushort_t* __restrict__ W1,
    ushort_t* __restrict__ o0h, ushort_t* __restrict__ o0l,
    ushort_t* __restrict__ o1h, ushort_t* __restrict__ o1l,
    const float* __restrict__ gamma, const float* __restrict__ beta,
    const float* __restrict__ mean, const float* __restrict__ var, int bnflag,
    int act) {
  __shared__ ushort_t Xh[64 * 40], Xl[64 * 40];   // [m][k] pad 32->40
  __shared__ ushort_t Wh[256 * 40], Wl[256 * 40]; // [oc][k]
  __shared__ float s_lds[256], sh_lds[256];
  const int tid = threadIdx.x;
  const int bx = blockIdx.x;
  const int pr = bx >> 3, pcs = bx & 7;
  const int b = blockIdx.y, z = blockIdx.z;
  const float* src = z ? src1 : src0;
  const ushort_t* Wq = z ? W1 : W0;
  ushort_t* ohi = z ? o1h : o0h;
  ushort_t* olo = z ? o1l : o0l;
  const int R0 = pr * 4, C0 = pcs * 16;
  if (bnflag) {
    float sv = gamma[tid] * rsqrtf(var[tid] + BN_EPS);
    s_lds[tid] = sv;
    sh_lds[tid] = beta[tid] - mean[tid] * sv;
  }
  const int w = tid >> 6, l = tid & 63, lr = l & 15, lh = l >> 4;
  f32x4 acc[4][4];
#pragma unroll
  for (int i = 0; i < 4; i++)
#pragma unroll
    for (int j = 0; j < 4; j++) acc[i][j] = 0.f;

  for (int kc = 0; kc < 8; ++kc) {
    int ic0 = kc * 32;
    __syncthreads();
    // --- X stage: fp32 global -> bf16 hi+lo, transposed to [m][k] ---
#pragma unroll
    for (int p = 0; p < 2; ++p) {
      int idx = p * 256 + tid;
      int ic = idx >> 4, rc = idx & 15, r = rc >> 2, c4 = rc & 3;
      const float* gp =
          src + (((size_t)(b * 256 + ic0 + ic) * 128 + R0 + r) * 128 + C0 +
                 c4 * 4);
      float4 v = *(const float4*)gp;
      if (bnflag) {
        float s = s_lds[ic0 + ic], sh = sh_lds[ic0 + ic];
        v.x = fmaf(v.x, s, sh);
        v.y = fmaf(v.y, s, sh);
        v.z = fmaf(v.z, s, sh);
        v.w = fmaf(v.w, s, sh);
      }
      int baserow = c4 * 16 + r * 4;
      const float* vp = &v.x;
#pragma unroll
      for (int q = 0; q < 4; ++q) {
        float f = vp[q];
        ushort_t hv = f2bf(f);
        Xh[(baserow + q) * 40 + ic] = hv;
        Xl[(baserow + q) * 40 + ic] = f2bf(f - bf2f(hv));
      }
    }
    // --- W stage: hi and lo halves ---
#pragma unroll
    for (int p = 0; p < 4; ++p) {
      int i = p * 256 + tid;
      int oc = i >> 2, slot = i & 3;
      *(uint4*)(&Wh[oc * 40 + slot * 8]) =
          *(const uint4*)(Wq + (size_t)oc * 512 + ic0 + slot * 8);
      *(uint4*)(&Wl[oc * 40 + slot * 8]) =
          *(const uint4*)(Wq + (size_t)oc * 512 + 256 + ic0 + slot * 8);
    }
    __syncthreads();
    bf16x8 ah[4], al[4], bh[4], bl[4];
#pragma unroll
    for (int mt = 0; mt < 4; ++mt) {
      ah[mt] = *(const bf16x8*)(&Xh[(mt * 16 + lr) * 40 + lh * 8]);
      al[mt] = *(const bf16x8*)(&Xl[(mt * 16 + lr) * 40 + lh * 8]);
    }
#pragma unroll
    for (int nt = 0; nt < 4; ++nt) {
      bh[nt] = *(const bf16x8*)(&Wh[(w * 64 + nt * 16 + lr) * 40 + lh * 8]);
      bl[nt] = *(const bf16x8*)(&Wl[(w * 64 + nt * 16 + lr) * 40 + lh * 8]);
    }
#pragma unroll
    for (int mt = 0; mt < 4; ++mt)
#pragma unroll
      for (int nt = 0; nt < 4; ++nt)
        acc[mt][nt] = __builtin_amdgcn_mfma_f32_16x16x32_bf16(
            ah[mt], bh[nt], acc[mt][nt], 0, 0, 0);
#pragma unroll
    for (int mt = 0; mt < 4; ++mt)
#pragma unroll
      for (int nt = 0; nt < 4; ++nt)
        acc[mt][nt] = __builtin_amdgcn_mfma_f32_16x16x32_bf16(
            al[mt], bh[nt], acc[mt][nt], 0, 0, 0);
#pragma unroll
    for (int mt = 0; mt < 4; ++mt)
#pragma unroll
      for (int nt = 0; nt < 4; ++nt)
        acc[mt][nt] = __builtin_amdgcn_mfma_f32_16x16x32_bf16(
            ah[mt], bl[nt], acc[mt][nt], 0, 0, 0);
  }
  // --- epilogue: pool 4x4 -> act -> split hi/lo -> store [px][oc] ---
#pragma unroll
  for (int mt = 0; mt < 4; ++mt) {
    int ppx = pr * 32 + pcs * 4 + mt;
#pragma unroll
    for (int nt = 0; nt < 4; ++nt) {
      f32x4 v = acc[mt][nt];
      float m0 = fmaxf(fmaxf(v[0], v[1]), fmaxf(v[2], v[3]));
      m0 = fmaxf(m0, __shfl_xor(m0, 16));
      m0 = fmaxf(m0, __shfl_xor(m0, 32));
      float r = act ? fmaxf(m0, 0.f) : 1.f / (1.f + expf(-m0));
      ushort_t hv = f2bf(r);
      ushort_t lv = f2bf(r - bf2f(hv));
      if (l < 16) {
        size_t o = (size_t)(b * 1024 + ppx) * 256 + w * 64 + nt * 16 + lr;
        ohi[o] = hv;
        olo[o] = lv;
      }
    }
  }
}

// ---------------------------------------------------------------------------
// Concat 1x1 conv (K=512 -> 256oc) on pooled bf16 hi/lo tensors, bf16x3.
// Inputs [b][1024px][C] so staging is a linear vector copy. Hi+lo staged
// together (X read once). Block = 64 px x 128 oc. grid(16, b*2+half, z).
__global__ __launch_bounds__(256) void cat_mfma_kernel(
    const ushort_t* Ah0, const ushort_t* Al0, const ushort_t* Bh0,
    const ushort_t* Bl0, const ushort_t* Wq0, ushort_t* oh0, ushort_t* ol0,
    float* of0, const ushort_t* Ah1, const ushort_t* Al1, const ushort_t* Bh1,
    const ushort_t* Bl1, const ushort_t* Wq1, ushort_t* oh1, ushort_t* ol1,
    float* of1, int CA, int sA, int sB, int fout) {
  __shared__ ushort_t Xh[64 * 40], Xl[64 * 40];
  __shared__ ushort_t Wh[128 * 40], Wl[128 * 40];
  __shared__ unsigned obuf[64 * 132];
  const int tid = threadIdx.x;
  const int PX0 = blockIdx.x * 64;
  const int b = blockIdx.y >> 1, OC0 = (blockIdx.y & 1) * 128;
  const int z = blockIdx.z;
  const ushort_t* Ah = z ? Ah1 : Ah0;
  const ushort_t* Al = z ? Al1 : Al0;
  const ushort_t* Bh = z ? Bh1 : Bh0;
  const ushort_t* Bl = z ? Bl1 : Bl0;
  const ushort_t* Wq = z ? Wq1 : Wq0;
  ushort_t* ohi = z ? oh1 : oh0;
  ushort_t* olo = z ? ol1 : ol0;
  float* of = z ? of1 : of0;
  const int w = tid >> 6, l = tid & 63, lr = l & 15, lh = l >> 4;
  f32x4 acc[4][2];
#pragma unroll
  for (int i = 0; i < 4; i++)
#pragma unroll
    for (int j = 0; j < 2; j++) acc[i][j] = 0.f;

  for (int kc = 0; kc < 16; ++kc) {
    int k0 = kc * 32;
    __syncthreads();
    {
      const ushort_t *xh, *xl;
      int cc0, st;
      if (k0 < CA) {
        xh = Ah; xl = Al; cc0 = k0; st = sA;
      } else {
        xh = Bh; xl = Bl; cc0 = k0 - CA; st = sB;
      }
      int px = tid >> 2, slot = tid & 3;
      size_t xo = (size_t)(b * 1024 + PX0 + px) * st + cc0 + slot * 8;
      *(uint4*)(&Xh[px * 40 + slot * 8]) = *(const uint4*)(xh + xo);
      *(uint4*)(&Xl[px * 40 + slot * 8]) = *(const uint4*)(xl + xo);
    }
#pragma unroll
    for (int p = 0; p < 2; ++p) {
      int i = p * 256 + tid;
      int oc = i >> 2, slot = i & 3;
      *(uint4*)(&Wh[oc * 40 + slot * 8]) =
          *(const uint4*)(Wq + (size_t)(OC0 + oc) * 1024 + k0 + slot * 8);
      *(uint4*)(&Wl[oc * 40 + slot * 8]) = *(const uint4*)(
          Wq + (size_t)(OC0 + oc) * 1024 + 512 + k0 + slot * 8);
    }
    __syncthreads();
    bf16x8 ah[4], al[4], bh[2], bl[2];
#pragma unroll
    for (int mt = 0; mt < 4; ++mt) {
      ah[mt] = *(const bf16x8*)(&Xh[(mt * 16 + lr) * 40 + lh * 8]);
      al[mt] = *(const bf16x8*)(&Xl[(mt * 16 + lr) * 40 + lh * 8]);
    }
#pragma unroll
    for (int nt = 0; nt < 2; ++nt) {
      bh[nt] = *(const bf16x8*)(&Wh[(w * 32 + nt * 16 + lr) * 40 + lh * 8]);
      bl[nt] = *(const bf16x8*)(&Wl[(w * 32 + nt * 16 + lr) * 40 + lh * 8]);
    }
#pragma unroll
    for (int mt = 0; mt < 4; ++mt)
#pragma unroll
      for (int nt = 0; nt < 2; ++nt)
        acc[mt][nt] = __builtin_amdgcn_mfma_f32_16x16x32_bf16(
            ah[mt], bh[nt], acc[mt][nt], 0, 0, 0);
#pragma unroll
    for (int mt = 0; mt < 4; ++mt)
#pragma unroll
      for (int nt = 0; nt < 2; ++nt)
        acc[mt][nt] = __builtin_amdgcn_mfma_f32_16x16x32_bf16(
            al[mt], bh[nt], acc[mt][nt], 0, 0, 0);
#pragma unroll
    for (int mt = 0; mt < 4; ++mt)
#pragma unroll
      for (int nt = 0; nt < 2; ++nt)
        acc[mt][nt] = __builtin_amdgcn_mfma_f32_16x16x32_bf16(
            ah[mt], bl[nt], acc[mt][nt], 0, 0, 0);
  }
  if (fout) {
#pragma unroll
    for (int mt = 0; mt < 4; ++mt)
#pragma unroll
      for (int nt = 0; nt < 2; ++nt) {
        int oc = OC0 + w * 32 + nt * 16 + lr;
        int px0 = PX0 + mt * 16 + lh * 4;
        float4 vv = make_float4(acc[mt][nt][0], acc[mt][nt][1], acc[mt][nt][2],
                                acc[mt][nt][3]);
        *(float4*)(of + ((size_t)(b * 256 + oc) * 1024 + px0)) = vv;
      }
  } else {
    __syncthreads();
#pragma unroll
    for (int mt = 0; mt < 4; ++mt)
#pragma unroll
      for (int nt = 0; nt < 2; ++nt)
#pragma unroll
        for (int j = 0; j < 4; ++j) {
          float f = acc[mt][nt][j];
          ushort_t hv = f2bf(f);
          ushort_t lv = f2bf(f - bf2f(hv));
          obuf[(mt * 16 + lh * 4 + j) * 132 + w * 32 + nt * 16 + lr] =
              (unsigned)hv | ((unsigned)lv << 16);
        }
    __syncthreads();
    int px = tid >> 2;
#pragma unroll
    for (int g = 0; g < 4; ++g) {
      int og = (tid & 3) * 32 + g * 8;
      ushort_t h8[8], l8[8];
#pragma unroll
      for (int q = 0; q < 8; ++q) {
        unsigned u = obuf[px * 132 + og + q];
        h8[q] = u & 0xffff;
        l8[q] = u >> 16;
      }
      size_t o = (size_t)(b * 1024 + PX0 + px) * 256 + OC0 + og;
      *(uint4*)(ohi + o) = pk8(h8);
      *(uint4*)(olo + o) = pk8(l8);
    }
  }
}

// ---------------------------------------------------------------------------
// avgpool grads -> grid-sample coefficients (flat corner px + weights).
__global__ void grads_pool_kernel(const float* __restrict__ grads,
                                  int4* __restrict__ pxi1,
                                  float4* __restrict__ w1,
                                  int4* __restrict__ pxi2,
                                  float4* __restrict__ w2) {
  unsigned flat = blockIdx.x * 256u + threadIdx.x;  // 0..4095
  unsigned pw = flat & 31u, ph = (flat >> 5) & 31u, b = flat >> 10;
  const float* gx = grads + (size_t)(b * 2 + 0) * 16384;
  const float* gy = grads + (size_t)(b * 2 + 1) * 16384;
  float sx_ = 0.f, sy_ = 0.f;
#pragma unroll
  for (int r = 0; r < 4; r++) {
    const float* rx = gx + (ph * 4 + r) * 128 + pw * 4;
    const float* ry = gy + (ph * 4 + r) * 128 + pw * 4;
#pragma unroll
    for (int q = 0; q < 4; q++) {
      sx_ += rx[q];
      sy_ += ry[q];
    }
  }
  float gxa = sx_ * (1.f / 16.f) * (1.f / 32.f);
  float gya = sy_ * (1.f / 16.f) * (1.f / 32.f);
  float basex = -1.f + pw * (2.f / 31.f);
  float basey = -1.f + ph * (2.f / 31.f);
  unsigned sidx = b * 1024u + ph * 32u + pw;
#pragma unroll
  for (int s = 0; s < 2; ++s) {
    float sgn = s ? -1.f : 1.f;
    float sx = (basex + sgn * gxa + 1.f) * 15.5f;
    float sy = (basey + sgn * gya + 1.f) * 15.5f;
    float x0f = floorf(sx), y0f = floorf(sy);
    float wx = sx - x0f, wy = sy - y0f;
    int x0 = (int)x0f, y0 = (int)y0f;
    bool vx0 = (x0f >= 0.f) && (x0f <= 31.f);
    bool vx1 = (x0f + 1.f >= 0.f) && (x0f + 1.f <= 31.f);
    bool vy0 = (y0f >= 0.f) && (y0f <= 31.f);
    bool vy1 = (y0f + 1.f >= 0.f) && (y0f + 1.f <= 31.f);
    int x0c = min(max(x0, 0), 31), x1c = min(max(x0 + 1, 0), 31);
    int y0c = min(max(y0, 0), 31), y1c = min(max(y0 + 1, 0), 31);
    int4 pi = make_int4(y0c * 32 + x0c, y0c * 32 + x1c, y1c * 32 + x0c,
                        y1c * 32 + x1c);
    float4 ww =
        make_float4((1.f - wx) * (1.f - wy) * ((vx0 && vy0) ? 1.f : 0.f),
                    wx * (1.f - wy) * ((vx1 && vy0) ? 1.f : 0.f),
                    (1.f - wx) * wy * ((vx0 && vy1) ? 1.f : 0.f),
                    wx * wy * ((vx1 && vy1) ? 1.f : 0.f));
    if (s == 0) {
      pxi1[sidx] = pi;
      w1[sidx] = ww;
    } else {
      pxi2[sidx] = pi;
      w2[sidx] = ww;
    }
  }
}

// ---------------------------------------------------------------------------
// m = grid_sample(m_prev) * a on hi/lo bf16 [b][1024][256]; both branches.
__global__ __launch_bounds__(256) void gs_mul_kernel(
    const ushort_t* c0h, const ushort_t* c0l, const ushort_t* a0h,
    const ushort_t* a0l, const int4* pxi0, const float4* wg0, ushort_t* o0h,
    ushort_t* o0l, const ushort_t* c1h, const ushort_t* c1l,
    const ushort_t* a1h, const ushort_t* a1l, const int4* pxi1,
    const float4* wg1, ushort_t* o1h, ushort_t* o1l) {
  unsigned flat = blockIdx.x * 256u + threadIdx.x;
  unsigned cg = flat & 31u;
  unsigned px = (flat >> 5) & 1023u;
  unsigned b = (flat >> 15) & 3u;
  unsigned br = flat >> 17;
  const ushort_t* ch = br ? c1h : c0h;
  const ushort_t* cl = br ? c1l : c0l;
  const ushort_t* ah = br ? a1h : a0h;
  const ushort_t* al = br ? a1l : a0l;
  const int4* pxi = br ? pxi1 : pxi0;
  const float4* wg = br ? wg1 : wg0;
  ushort_t* ohp = br ? o1h : o0h;
  ushort_t* olp = br ? o1l : o0l;
  int4 pi = pxi[b * 1024 + px];
  float4 wv = wg[b * 1024 + px];
  size_t rb = (size_t)b * 1024;
  int co = cg * 8;
  float v[8];
#pragma unroll
  for (int j = 0; j < 8; ++j) v[j] = 0.f;
  const int rows[4] = {pi.x, pi.y, pi.z, pi.w};
  const float wks[4] = {wv.x, wv.y, wv.z, wv.w};
#pragma unroll
  for (int k = 0; k < 4; ++k) {
    size_t o = (rb + rows[k]) * 256 + co;
    uint4 hu = *(const uint4*)(ch + o);
    uint4 lu = *(const uint4*)(cl + o);
    ushort_t h8[8], l8[8];
    unp8(hu, h8);
    unp8(lu, l8);
    float wk = wks[k];
#pragma unroll
    for (int j = 0; j < 8; ++j)
      v[j] = fmaf(wk, bf2f(h8[j]) + bf2f(l8[j]), v[j]);
  }
  size_t oo = (rb + px) * 256 + co;
  uint4 ahu = *(const uint4*)(ah + oo);
  uint4 alu = *(const uint4*)(al + oo);
  ushort_t ah8[8], al8[8];
  unp8(ahu, ah8);
  unp8(alu, al8);
  ushort_t rh[8], rl[8];
#pragma unroll
  for (int j = 0; j < 8; ++j) {
    float r = v[j] * (bf2f(ah8[j]) + bf2f(al8[j]));
    rh[j] = f2bf(r);
    rl[j] = f2bf(r - bf2f(rh[j]));
  }
  *(uint4*)(ohp + oo) = pk8(rh);
  *(uint4*)(olp + oo) = pk8(rl);
}

// ---------------------------------------------------------------------------
// merge depthwise 3x3 on concat(ms1,ms2)/ITERS, hi/lo in -> hi/lo out
// [b][1024][512]. Block: 32 pc x 8 cgroups (64 channels window).
__global__ __launch_bounds__(256) void merge_dw_kernel(
    const ushort_t* s1h, const ushort_t* s1l, const ushort_t* s2h,
    const ushort_t* s2l, const float* __restrict__ wall, ushort_t* dh,
    ushort_t* dl) {
  __shared__ float wlds[576];
  int bx = blockIdx.x;
  int pr = bx >> 3, cset = bx & 7;
  int b = blockIdx.y;
  int pc = threadIdx.x & 31, cg = threadIdx.x >> 5;
  for (int i = threadIdx.x; i < 576; i += 256) wlds[i] = wall[cset * 576 + i];
  __syncthreads();
  const ushort_t* sh_ = (cset < 4) ? s1h : s2h;
  const ushort_t* sl_ = (cset < 4) ? s1l : s2l;
  int csrc = (cset & 3) * 64 + cg * 8;
  float acc[8];
#pragma unroll
  for (int j = 0; j < 8; ++j) acc[j] = 0.f;
#pragma unroll
  for (int dr = -1; dr <= 1; ++dr) {
    int r2 = pr + dr;
    if (r2 < 0 || r2 > 31) continue;
#pragma unroll
    for (int dc = -1; dc <= 1; ++dc) {
      int c2 = pc + dc;
      if (c2 < 0 || c2 > 31) continue;
      size_t o = ((size_t)(b * 1024) + r2 * 32 + c2) * 256 + csrc;
      uint4 hu = *(const uint4*)(sh_ + o);
      uint4 lu = *(const uint4*)(sl_ + o);
      ushort_t h8[8], l8[8];
      unp8(hu, h8);
      unp8(lu, l8);
      int wi = (dr + 1) * 3 + (dc + 1);
#pragma unroll
      for (int j = 0; j < 8; ++j)
        acc[j] = fmaf(wlds[(cg * 8 + j) * 9 + wi], bf2f(h8[j]) + bf2f(l8[j]),
                      acc[j]);
    }
  }
  size_t oo = ((size_t)(b * 1024) + pr * 32 + pc) * 512 + cset * 64 + cg * 8;
  ushort_t h8[8], l8[8];
#pragma unroll
  for (int j = 0; j < 8; ++j) {
    float f = acc[j] * 0.1f;
    h8[j] = f2bf(f);
    l8[j] = f2bf(f - bf2f(h8[j]));
  }
  *(uint4*)(dh + oo) = pk8(h8);
  *(uint4*)(dl + oo) = pk8(l8);
}

// ---------------------------------------------------------------------------
// bilinear upsample 32->128, align_corners=True, from fp32 [b][256][1024].
__global__ __launch_bounds__(256) void upsample_kernel(
    const float* __restrict__ mid, float* __restrict__ out) {
  unsigned flat = blockIdx.x * 256u + threadIdx.x;  // f4 units
  unsigned ow4 = flat & 31u;
  unsigned oh = (flat >> 5) & 127u;
  unsigned bc = flat >> 12;  // b*256+c
  const float* pl = mid + (size_t)bc * 1024;
  float rh = oh * (31.f / 127.f);
  float ihf = floorf(rh);
  float wh = rh - ihf;
  int i0 = (int)ihf;
  int i1 = min(i0 + 1, 31);
  const float* r0 = pl + i0 * 32;
  const float* r1 = pl + i1 * 32;
  float4 res;
  float* rp = &res.x;
#pragma unroll
  for (int j = 0; j < 4; j++) {
    unsigned ow = ow4 * 4 + j;
    float rw = ow * (31.f / 127.f);
    float jwf = floorf(rw);
    float ww = rw - jwf;
    int j0 = (int)jwf;
    int j1 = min(j0 + 1, 31);
    float top = r0[j0] * (1.f - ww) + r0[j1] * ww;
    float bot = r1[j0] * (1.f - ww) + r1[j1] * ww;
    rp[j] = top * (1.f - wh) + bot * wh;
  }
  reinterpret_cast<float4*>(out)[flat] = res;
}

// ---------------------------------------------------------------------------
extern "C" void kernel_launch(void* const* d_in, const int* in_sizes, int n_in,
                              void* d_out, int out_size, void* d_ws,
                              size_t ws_size, hipStream_t stream) {
  (void)in_sizes;
  (void)n_in;
  (void)out_size;
  (void)ws_size;
  const float* x = (const float*)d_in[0];
  const float* grads = (const float*)d_in[1];
  const float* bn_gamma = (const float*)d_in[2];
  const float* bn_beta = (const float*)d_in[3];
  const float* bn_mean = (const float*)d_in[4];
  const float* bn_var = (const float*)d_in[5];
  const float* att1_dw = (const float*)d_in[6];
  const float* att1_pw = (const float*)d_in[7];
  const float* att2_dw = (const float*)d_in[8];
  const float* att2_pw = (const float*)d_in[9];
  const float* conv1_w = (const float*)d_in[10];
  const float* conv2_w = (const float*)d_in[11];
  const float* add1_w = (const float*)d_in[12];
  const float* add2_w = (const float*)d_in[13];
  const float* merge_dww = (const float*)d_in[14];
  const float* merge_pww = (const float*)d_in[15];
  float* out = (float*)d_out;

  const size_t MB = 1u << 20;
  uint8_t* base = (uint8_t*)d_ws;
  float* t1 = (float*)base;  // 64 MB scratch, dead after att pw launches
  uint8_t* P = base + 64 * MB;
  ushort_t* wAtt1 = (ushort_t*)P; P += 262144;
  ushort_t* wAtt2 = (ushort_t*)P; P += 262144;
  ushort_t* wC1 = (ushort_t*)P; P += 262144;
  ushort_t* wC2 = (ushort_t*)P; P += 262144;
  ushort_t* wAdd1 = (ushort_t*)P; P += 524288;
  ushort_t* wAdd2 = (ushort_t*)P; P += 524288;
  ushort_t* wMrg = (ushort_t*)P; P += 524288;
  ushort_t* a1h = (ushort_t*)P; P += 2 * MB;
  ushort_t* a1l = (ushort_t*)P; P += 2 * MB;
  ushort_t* a2h = (ushort_t*)P; P += 2 * MB;
  ushort_t* a2l = (ushort_t*)P; P += 2 * MB;
  ushort_t* m1Ph = (ushort_t*)P; P += 2 * MB;
  ushort_t* m1Pl = (ushort_t*)P; P += 2 * MB;
  ushort_t* m2Ph = (ushort_t*)P; P += 2 * MB;
  ushort_t* m2Pl = (ushort_t*)P; P += 2 * MB;
  int4* pxi1 = (int4*)P; P += 65536;
  float4* w1g = (float4*)P; P += 65536;
  int4* pxi2 = (int4*)P; P += 65536;
  float4* w2g = (float4*)P; P += 65536;
  // loop region reuses the t1 area (36 MB < 64 MB), live only after att pw
  uint8_t* Q = base;
  ushort_t* m1Qh = (ushort_t*)Q; Q += 2 * MB;
  ushort_t* m1Ql = (ushort_t*)Q; Q += 2 * MB;
  ushort_t* m2Qh = (ushort_t*)Q; Q += 2 * MB;
  ushort_t* m2Ql = (ushort_t*)Q; Q += 2 * MB;
  ushort_t* s1ah = (ushort_t*)Q; Q += 2 * MB;
  ushort_t* s1al = (ushort_t*)Q; Q += 2 * MB;
  ushort_t* s1bh = (ushort_t*)Q; Q += 2 * MB;
  ushort_t* s1bl = (ushort_t*)Q; Q += 2 * MB;
  ushort_t* s2ah = (ushort_t*)Q; Q += 2 * MB;
  ushort_t* s2al = (ushort_t*)Q; Q += 2 * MB;
  ushort_t* s2bh = (ushort_t*)Q; Q += 2 * MB;
  ushort_t* s2bl = (ushort_t*)Q; Q += 2 * MB;
  ushort_t* dwmh = (ushort_t*)Q; Q += 4 * MB;
  ushort_t* dwml = (ushort_t*)Q; Q += 4 * MB;
  float* mid = (float*)Q; Q += 4 * MB;

  wsplit_kernel<<<1792, 256, 0, stream>>>(att1_pw, att2_pw, conv1_w, conv2_w,
                                          add1_w, add2_w, merge_pww, wAtt1,
                                          wAtt2, wC1, wC2, wAdd1, wAdd2, wMrg);
  // m-branch convs straight from x (BN in staging), relu+pool
  pw_mfma_kernel<<<dim3(256, 4, 2), 256, 0, stream>>>(
      x, x, wC1, wC2, m1Ph, m1Pl, m2Ph, m2Pl, bn_gamma, bn_beta, bn_mean,
      bn_var, 1, 1);
  // attention branch 1: dw(BN(x)) -> t1 -> pw+sigmoid+pool
  dw_bn_kernel<<<16384, 256, 0, stream>>>(x, att1_dw, bn_gamma, bn_beta,
                                          bn_mean, bn_var, t1);
  pw_mfma_kernel<<<dim3(256, 4, 1), 256, 0, stream>>>(
      t1, t1, wAtt1, wAtt1, a1h, a1l, a1h, a1l, bn_gamma, bn_beta, bn_mean,
      bn_var, 0, 0);
  // attention branch 2 (reuses t1)
  dw_bn_kernel<<<16384, 256, 0, stream>>>(x, att2_dw, bn_gamma, bn_beta,
                                          bn_mean, bn_var, t1);
  pw_mfma_kernel<<<dim3(256, 4, 1), 256, 0, stream>>>(
      t1, t1, wAtt2, wAtt2, a2h, a2l, a2h, a2l, bn_gamma, bn_beta, bn_mean,
      bn_var, 0, 0);
  grads_pool_kernel<<<16, 256, 0, stream>>>(grads, pxi1, w1g, pxi2, w2g);

  const ushort_t *c1h = m1Ph, *c1l = m1Pl, *c2h = m2Ph, *c2l = m2Pl;
  const ushort_t *ss1h = m1Ph, *ss1l = m1Pl, *ss2h = m2Ph, *ss2l = m2Pl;
  for (int it = 0; it < 10; ++it) {
    ushort_t* n1h = (it & 1) ? m1Ph : m1Qh;
    ushort_t* n1l = (it & 1) ? m1Pl : m1Ql;
    ushort_t* n2h = (it & 1) ? m2Ph : m2Qh;
    ushort_t* n2l = (it & 1) ? m2Pl : m2Ql;
    gs_mul_kernel<<<1024, 256, 0, stream>>>(c1h, c1l, a1h, a1l, pxi1, w1g, n1h,
                                            n1l, c2h, c2l, a2h, a2l, pxi2, w2g,
                                            n2h, n2l);
    ushort_t* so1h = (it & 1) ? s1bh : s1ah;
    ushort_t* so1l = (it & 1) ? s1bl : s1al;
    ushort_t* so2h = (it & 1) ? s2bh : s2ah;
    ushort_t* so2l = (it & 1) ? s2bl : s2al;
    cat_mfma_kernel<<<dim3(16, 8, 2), 256, 0, stream>>>(
        ss1h, ss1l, n1h, n1l, wAdd1, so1h, so1l, nullptr, ss2h, ss2l, n2h, n2l,
        wAdd2, so2h, so2l, nullptr, 256, 256, 256, 0);
    c1h = n1h; c1l = n1l; c2h = n2h; c2l = n2l;
    ss1h = so1h; ss1l = so1l; ss2h = so2h; ss2l = so2l;
  }
  merge_dw_kernel<<<dim3(256, 4), 256, 0, stream>>>(ss1h, ss1l, ss2h, ss2l,
                                                    merge_dww, dwmh, dwml);
  cat_mfma_kernel<<<dim3(16, 8, 1), 256, 0, stream>>>(
      dwmh, dwml, dwmh, dwml, wMrg, nullptr, nullptr, mid, dwmh, dwml, dwmh,
      dwml, wMrg, nullptr, nullptr, mid, 512, 512, 512, 1);
  upsample_kernel<<<16384, 256, 0, stream>>>(mid, out);
}

// Round 4
// 663.877 us; speedup vs baseline: 1.8889x; 1.0609x over previous
//
#include <hip/hip_runtime.h>
#include <cstddef>
#include <cstdint>

#define BN_EPS 1e-5f
typedef unsigned short ushort_t;
typedef __attribute__((ext_vector_type(8))) short bf16x8;
typedef __attribute__((ext_vector_type(4))) float f32x4;

__device__ __forceinline__ ushort_t f2bf(float f) {
  unsigned u = __float_as_uint(f);
  unsigned r = (u + 0x7fffu + ((u >> 16) & 1u)) >> 16;
  return (ushort_t)r;
}
__device__ __forceinline__ float bf2f(ushort_t h) {
  return __uint_as_float(((unsigned)h) << 16);
}
__device__ __forceinline__ float upk(unsigned u) {
  return bf2f((ushort_t)(u & 0xffff)) + bf2f((ushort_t)(u >> 16));
}
__device__ __forceinline__ unsigned pkpair(float f) {
  ushort_t h = f2bf(f);
  return (unsigned)h | ((unsigned)f2bf(f - bf2f(h)) << 16);
}
__device__ __forceinline__ uint4 pk8(const ushort_t* d) {
  uint4 u;
  u.x = (unsigned)d[0] | ((unsigned)d[1] << 16);
  u.y = (unsigned)d[2] | ((unsigned)d[3] << 16);
  u.z = (unsigned)d[4] | ((unsigned)d[5] << 16);
  u.w = (unsigned)d[6] | ((unsigned)d[7] << 16);
  return u;
}

// ---------------------------------------------------------------------------
// Weight split: fp32 [256][K] -> bf16 [256][2K] = [hi(K) | lo(K)].
__global__ __launch_bounds__(256) void wsplit_kernel(
    const float* s0, const float* s1, const float* s2, const float* s3,
    const float* s4, const float* s5, const float* s6, ushort_t* d0,
    ushort_t* d1, ushort_t* d2, ushort_t* d3, ushort_t* d4, ushort_t* d5,
    ushort_t* d6) {
  int r = blockIdx.x;
  int tid = threadIdx.x;
  if (r < 1024) {
    int wi = r >> 8, oc = r & 255;
    const float* s = wi == 0 ? s0 : wi == 1 ? s1 : wi == 2 ? s2 : s3;
    ushort_t* d = wi == 0 ? d0 : wi == 1 ? d1 : wi == 2 ? d2 : d3;
    float v = s[oc * 256 + tid];
    ushort_t h = f2bf(v);
    d[oc * 512 + tid] = h;
    d[oc * 512 + 256 + tid] = f2bf(v - bf2f(h));
  } else {
    int rr = r - 1024;
    int wi = rr >> 8, oc = rr & 255;
    const float* s = wi == 0 ? s4 : wi == 1 ? s5 : s6;
    ushort_t* d = wi == 0 ? d4 : wi == 1 ? d5 : d6;
#pragma unroll
    for (int p = 0; p < 2; ++p) {
      int k = p * 256 + tid;
      float v = s[oc * 512 + k];
      ushort_t h = f2bf(v);
      d[oc * 1024 + k] = h;
      d[oc * 1024 + 512 + k] = f2bf(v - bf2f(h));
    }
  }
}

// ---------------------------------------------------------------------------
// Depthwise 3x3 pad1 with BN folded into input loads (single branch).
__global__ __launch_bounds__(256) void dw_bn_kernel(
    const float* __restrict__ x, const float* __restrict__ wall,
    const float* __restrict__ gamma, const float* __restrict__ beta,
    const float* __restrict__ mean, const float* __restrict__ var,
    float* __restrict__ out) {
  int blk = blockIdx.x;
  int sub = blk & 15;
  int bc = blk >> 4;  // b*256+c
  int c = bc & 255;
  float s = gamma[c] * rsqrtf(var[c] + BN_EPS);
  float sh = beta[c] - mean[c] * s;
  int row = sub * 8 + (threadIdx.x >> 5);
  int col4 = threadIdx.x & 31;
  const float* w = wall + c * 9;
  const float* base = x + (size_t)bc * 16384;
  float4 acc = make_float4(0.f, 0.f, 0.f, 0.f);
#pragma unroll
  for (int dr = -1; dr <= 1; dr++) {
    int rr = row + dr;
    if (rr < 0 || rr > 127) continue;
    const float* rp = base + rr * 128;
    float4 v = reinterpret_cast<const float4*>(rp)[col4];
    v.x = fmaf(v.x, s, sh);
    v.y = fmaf(v.y, s, sh);
    v.z = fmaf(v.z, s, sh);
    v.w = fmaf(v.w, s, sh);
    float lf = col4 ? fmaf(rp[col4 * 4 - 1], s, sh) : 0.f;
    float rg = (col4 < 31) ? fmaf(rp[col4 * 4 + 4], s, sh) : 0.f;
    float k0 = w[(dr + 1) * 3 + 0];
    float k1 = w[(dr + 1) * 3 + 1];
    float k2 = w[(dr + 1) * 3 + 2];
    acc.x = fmaf(k0, lf, fmaf(k1, v.x, fmaf(k2, v.y, acc.x)));
    acc.y = fmaf(k0, v.x, fmaf(k1, v.y, fmaf(k2, v.z, acc.y)));
    acc.z = fmaf(k0, v.y, fmaf(k1, v.z, fmaf(k2, v.w, acc.z)));
    acc.w = fmaf(k0, v.z, fmaf(k1, v.w, fmaf(k2, rg, acc.w)));
  }
  reinterpret_cast<float4*>(out + (size_t)bc * 16384 + row * 128)[col4] = acc;
}

// ---------------------------------------------------------------------------
// MFMA 1x1 conv (256->256, bf16x3 split) over full res, fused 4x4 maxpool +
// activation, register-prefetch staged. Out: packed (hi|lo) [b][1024][256].
__global__ __launch_bounds__(256) void pw_mfma_kernel(
    const float* __restrict__ src0, const float* __restrict__ src1,
    const ushort_t* __restrict__ W0, const ushort_t* __restrict__ W1,
    unsigned* __restrict__ o0, unsigned* __restrict__ o1,
    const float* __restrict__ gamma, const float* __restrict__ beta,
    const float* __restrict__ mean, const float* __restrict__ var, int bnflag,
    int act) {
  __shared__ ushort_t Xh[64 * 40], Xl[64 * 40];
  __shared__ ushort_t Wh[256 * 40], Wl[256 * 40];
  __shared__ float s_lds[256], sh_lds[256];
  const int tid = threadIdx.x;
  const int bx = blockIdx.x;
  const int pr = bx >> 3, pcs = bx & 7;
  const int b = blockIdx.y, z = blockIdx.z;
  const float* src = z ? src1 : src0;
  const ushort_t* Wq = z ? W1 : W0;
  unsigned* op = z ? o1 : o0;
  const int R0 = pr * 4, C0 = pcs * 16;
  if (bnflag) {
    float sv = gamma[tid] * rsqrtf(var[tid] + BN_EPS);
    s_lds[tid] = sv;
    sh_lds[tid] = beta[tid] - mean[tid] * sv;
  } else {
    s_lds[tid] = 1.f;
    sh_lds[tid] = 0.f;
  }
  __syncthreads();
  const int w = tid >> 6, l = tid & 63, lr = l & 15, lh = l >> 4;
  f32x4 acc[4][4];
#pragma unroll
  for (int i = 0; i < 4; i++)
#pragma unroll
    for (int j = 0; j < 4; j++) acc[i][j] = 0.f;

  float4 xf0, xf1;  // X prefetch registers
  auto LDXP = [&](int kc) {
    int ic0 = kc * 32;
    {
      int idx = tid;
      int ic = idx >> 4, rc = idx & 15, r = rc >> 2, c4 = rc & 3;
      xf0 = *(const float4*)(src + (((size_t)(b * 256 + ic0 + ic) * 128 + R0 +
                                     r) * 128 + C0 + c4 * 4));
    }
    {
      int idx = 256 + tid;
      int ic = idx >> 4, rc = idx & 15, r = rc >> 2, c4 = rc & 3;
      xf1 = *(const float4*)(src + (((size_t)(b * 256 + ic0 + ic) * 128 + R0 +
                                     r) * 128 + C0 + c4 * 4));
    }
  };
  auto WRXP = [&](int kc) {
    int ic0 = kc * 32;
#pragma unroll
    for (int p = 0; p < 2; ++p) {
      int idx = p * 256 + tid;
      int ic = idx >> 4, rc = idx & 15, r = rc >> 2, c4 = rc & 3;
      float4 v = p ? xf1 : xf0;
      float s = s_lds[ic0 + ic], sh = sh_lds[ic0 + ic];
      v.x = fmaf(v.x, s, sh);
      v.y = fmaf(v.y, s, sh);
      v.z = fmaf(v.z, s, sh);
      v.w = fmaf(v.w, s, sh);
      int baserow = c4 * 16 + r * 4;
      const float* vp = &v.x;
#pragma unroll
      for (int q = 0; q < 4; ++q) {
        float f = vp[q];
        ushort_t hv = f2bf(f);
        Xh[(baserow + q) * 40 + ic] = hv;
        Xl[(baserow + q) * 40 + ic] = f2bf(f - bf2f(hv));
      }
    }
  };
  auto WSTG = [&](int kc) {
    int ic0 = kc * 32;
#pragma unroll
    for (int p = 0; p < 4; ++p) {
      int i = p * 256 + tid;
      int oc = i >> 2, slot = i & 3;
      *(uint4*)(&Wh[oc * 40 + slot * 8]) =
          *(const uint4*)(Wq + (size_t)oc * 512 + ic0 + slot * 8);
      *(uint4*)(&Wl[oc * 40 + slot * 8]) =
          *(const uint4*)(Wq + (size_t)oc * 512 + 256 + ic0 + slot * 8);
    }
  };
  LDXP(0);
  WRXP(0);
  WSTG(0);
  __syncthreads();
  for (int kc = 0; kc < 8; ++kc) {
    if (kc < 7) LDXP(kc + 1);
    bf16x8 ah[4], al[4], bh[4], bl[4];
#pragma unroll
    for (int mt = 0; mt < 4; ++mt) {
      ah[mt] = *(const bf16x8*)(&Xh[(mt * 16 + lr) * 40 + lh * 8]);
      al[mt] = *(const bf16x8*)(&Xl[(mt * 16 + lr) * 40 + lh * 8]);
    }
#pragma unroll
    for (int nt = 0; nt < 4; ++nt) {
      bh[nt] = *(const bf16x8*)(&Wh[(w * 64 + nt * 16 + lr) * 40 + lh * 8]);
      bl[nt] = *(const bf16x8*)(&Wl[(w * 64 + nt * 16 + lr) * 40 + lh * 8]);
    }
#pragma unroll
    for (int mt = 0; mt < 4; ++mt)
#pragma unroll
      for (int nt = 0; nt < 4; ++nt)
        acc[mt][nt] = __builtin_amdgcn_mfma_f32_16x16x32_bf16(
            ah[mt], bh[nt], acc[mt][nt], 0, 0, 0);
#pragma unroll
    for (int mt = 0; mt < 4; ++mt)
#pragma unroll
      for (int nt = 0; nt < 4; ++nt)
        acc[mt][nt] = __builtin_amdgcn_mfma_f32_16x16x32_bf16(
            al[mt], bh[nt], acc[mt][nt], 0, 0, 0);
#pragma unroll
    for (int mt = 0; mt < 4; ++mt)
#pragma unroll
      for (int nt = 0; nt < 4; ++nt)
        acc[mt][nt] = __builtin_amdgcn_mfma_f32_16x16x32_bf16(
            ah[mt], bl[nt], acc[mt][nt], 0, 0, 0);
    if (kc < 7) {
      __syncthreads();
      WRXP(kc + 1);
      WSTG(kc + 1);
      __syncthreads();
    }
  }
  // epilogue: pool 4x4 -> act -> packed store [px][oc]
#pragma unroll
  for (int mt = 0; mt < 4; ++mt) {
    int ppx = pr * 32 + pcs * 4 + mt;
#pragma unroll
    for (int nt = 0; nt < 4; ++nt) {
      f32x4 v = acc[mt][nt];
      float m0 = fmaxf(fmaxf(v[0], v[1]), fmaxf(v[2], v[3]));
      m0 = fmaxf(m0, __shfl_xor(m0, 16));
      m0 = fmaxf(m0, __shfl_xor(m0, 32));
      float r = act ? fmaxf(m0, 0.f) : 1.f / (1.f + expf(-m0));
      if (l < 16)
        op[(size_t)(b * 1024 + ppx) * 256 + w * 64 + nt * 16 + lr] = pkpair(r);
    }
  }
}

// ---------------------------------------------------------------------------
// Concat 1x1 conv (K=512 -> 256oc) on packed (hi|lo) tensors, bf16x3 split.
// 128-thread blocks, 32px x 64oc tile, reg-prefetch staging.
// grid (128 strips [b*32 + px/32], 4 oc-quarters, z). fout: fp32 [b][256][1024].
__global__ __launch_bounds__(128) void catp_kernel(
    const unsigned* A0, const unsigned* B0, const ushort_t* W0, unsigned* op0,
    float* of0, const unsigned* A1, const unsigned* B1, const ushort_t* W1,
    unsigned* op1, float* of1, int CA, int sA, int sB, int fout) {
  __shared__ ushort_t Xh[32 * 40], Xl[32 * 40];
  __shared__ ushort_t Wh[64 * 40], Wl[64 * 40];
  const int tid = threadIdx.x;
  const int strip = blockIdx.x;
  const int b = strip >> 5;
  const int PX0 = (strip & 31) * 32;
  const int OC0 = blockIdx.y * 64;
  const int z = blockIdx.z;
  const unsigned* A = z ? A1 : A0;
  const unsigned* B = z ? B1 : B0;
  const ushort_t* Wq = z ? W1 : W0;
  unsigned* op = z ? op1 : op0;
  float* of = z ? of1 : of0;
  const int w = tid >> 6, l = tid & 63, lr = l & 15, lh = l >> 4;
  const int spx = tid >> 2, sslot = tid & 3;
  const int soc = tid >> 1, shalf = tid & 1;
  uint4 xr0, xr1, w0h, w1h, w0l, w1l;
  f32x4 acc[2][2];
#pragma unroll
  for (int i = 0; i < 2; i++)
#pragma unroll
    for (int j = 0; j < 2; j++) acc[i][j] = 0.f;

  auto LDX = [&](int kc) {
    int k0 = kc * 32;
    const unsigned* src;
    int cc0, st;
    if (k0 < CA) {
      src = A; cc0 = k0; st = sA;
    } else {
      src = B; cc0 = k0 - CA; st = sB;
    }
    const unsigned* p =
        src + ((size_t)(b * 1024 + PX0 + spx) * st + cc0 + sslot * 8);
    xr0 = *(const uint4*)p;
    xr1 = *(const uint4*)(p + 4);
    const ushort_t* wp = Wq + (size_t)(OC0 + soc) * 1024 + k0 + shalf * 16;
    w0h = *(const uint4*)wp;
    w1h = *(const uint4*)(wp + 8);
    w0l = *(const uint4*)(wp + 512);
    w1l = *(const uint4*)(wp + 520);
  };
  auto WRX = [&]() {
    ushort_t h8[8], l8[8];
    h8[0] = xr0.x & 0xffff; l8[0] = xr0.x >> 16;
    h8[1] = xr0.y & 0xffff; l8[1] = xr0.y >> 16;
    h8[2] = xr0.z & 0xffff; l8[2] = xr0.z >> 16;
    h8[3] = xr0.w & 0xffff; l8[3] = xr0.w >> 16;
    h8[4] = xr1.x & 0xffff; l8[4] = xr1.x >> 16;
    h8[5] = xr1.y & 0xffff; l8[5] = xr1.y >> 16;
    h8[6] = xr1.z & 0xffff; l8[6] = xr1.z >> 16;
    h8[7] = xr1.w & 0xffff; l8[7] = xr1.w >> 16;
    *(uint4*)(&Xh[spx * 40 + sslot * 8]) = pk8(h8);
    *(uint4*)(&Xl[spx * 40 + sslot * 8]) = pk8(l8);
    *(uint4*)(&Wh[soc * 40 + shalf * 16]) = w0h;
    *(uint4*)(&Wh[soc * 40 + shalf * 16 + 8]) = w1h;
    *(uint4*)(&Wl[soc * 40 + shalf * 16]) = w0l;
    *(uint4*)(&Wl[soc * 40 + shalf * 16 + 8]) = w1l;
  };
  LDX(0);
  WRX();
  __syncthreads();
  for (int kc = 0; kc < 16; ++kc) {
    if (kc < 15) LDX(kc + 1);
    bf16x8 ah[2], al[2], bh[2], bl[2];
#pragma unroll
    for (int mt = 0; mt < 2; ++mt) {
      ah[mt] = *(const bf16x8*)(&Xh[(mt * 16 + lr) * 40 + lh * 8]);
      al[mt] = *(const bf16x8*)(&Xl[(mt * 16 + lr) * 40 + lh * 8]);
    }
#pragma unroll
    for (int nt = 0; nt < 2; ++nt) {
      bh[nt] = *(const bf16x8*)(&Wh[(w * 32 + nt * 16 + lr) * 40 + lh * 8]);
      bl[nt] = *(const bf16x8*)(&Wl[(w * 32 + nt * 16 + lr) * 40 + lh * 8]);
    }
#pragma unroll
    for (int mt = 0; mt < 2; ++mt)
#pragma unroll
      for (int nt = 0; nt < 2; ++nt) {
        acc[mt][nt] = __builtin_amdgcn_mfma_f32_16x16x32_bf16(
            ah[mt], bh[nt], acc[mt][nt], 0, 0, 0);
        acc[mt][nt] = __builtin_amdgcn_mfma_f32_16x16x32_bf16(
            al[mt], bh[nt], acc[mt][nt], 0, 0, 0);
        acc[mt][nt] = __builtin_amdgcn_mfma_f32_16x16x32_bf16(
            ah[mt], bl[nt], acc[mt][nt], 0, 0, 0);
      }
    if (kc < 15) {
      __syncthreads();
      WRX();
      __syncthreads();
    }
  }
  if (fout) {
#pragma unroll
    for (int mt = 0; mt < 2; ++mt)
#pragma unroll
      for (int nt = 0; nt < 2; ++nt) {
        int oc = OC0 + w * 32 + nt * 16 + lr;
        int px0 = PX0 + mt * 16 + lh * 4;
        float4 vv = make_float4(acc[mt][nt][0], acc[mt][nt][1], acc[mt][nt][2],
                                acc[mt][nt][3]);
        *(float4*)(of + ((size_t)(b * 256 + oc) * 1024 + px0)) = vv;
      }
  } else {
#pragma unroll
    for (int mt = 0; mt < 2; ++mt)
#pragma unroll
      for (int nt = 0; nt < 2; ++nt) {
        int oc = OC0 + w * 32 + nt * 16 + lr;
#pragma unroll
        for (int j = 0; j < 4; ++j) {
          int px = PX0 + mt * 16 + lh * 4 + j;
          op[(size_t)(b * 1024 + px) * 256 + oc] = pkpair(acc[mt][nt][j]);
        }
      }
  }
}

// ---------------------------------------------------------------------------
// avgpool grads -> grid-sample coefficients (flat corner px + weights).
__global__ void grads_pool_kernel(const float* __restrict__ grads,
                                  int4* __restrict__ pxi1,
                                  float4* __restrict__ w1,
                                  int4* __restrict__ pxi2,
                                  float4* __restrict__ w2) {
  unsigned flat = blockIdx.x * 256u + threadIdx.x;  // 0..4095
  unsigned pw = flat & 31u, ph = (flat >> 5) & 31u, b = flat >> 10;
  const float* gx = grads + (size_t)(b * 2 + 0) * 16384;
  const float* gy = grads + (size_t)(b * 2 + 1) * 16384;
  float sx_ = 0.f, sy_ = 0.f;
#pragma unroll
  for (int r = 0; r < 4; r++) {
    const float* rx = gx + (ph * 4 + r) * 128 + pw * 4;
    const float* ry = gy + (ph * 4 + r) * 128 + pw * 4;
#pragma unroll
    for (int q = 0; q < 4; q++) {
      sx_ += rx[q];
      sy_ += ry[q];
    }
  }
  float gxa = sx_ * (1.f / 16.f) * (1.f / 32.f);
  float gya = sy_ * (1.f / 16.f) * (1.f / 32.f);
  float basex = -1.f + pw * (2.f / 31.f);
  float basey = -1.f + ph * (2.f / 31.f);
  unsigned sidx = b * 1024u + ph * 32u + pw;
#pragma unroll
  for (int s = 0; s < 2; ++s) {
    float sgn = s ? -1.f : 1.f;
    float sx = (basex + sgn * gxa + 1.f) * 15.5f;
    float sy = (basey + sgn * gya + 1.f) * 15.5f;
    float x0f = floorf(sx), y0f = floorf(sy);
    float wx = sx - x0f, wy = sy - y0f;
    int x0 = (int)x0f, y0 = (int)y0f;
    bool vx0 = (x0f >= 0.f) && (x0f <= 31.f);
    bool vx1 = (x0f + 1.f >= 0.f) && (x0f + 1.f <= 31.f);
    bool vy0 = (y0f >= 0.f) && (y0f <= 31.f);
    bool vy1 = (y0f + 1.f >= 0.f) && (y0f + 1.f <= 31.f);
    int x0c = min(max(x0, 0), 31), x1c = min(max(x0 + 1, 0), 31);
    int y0c = min(max(y0, 0), 31), y1c = min(max(y0 + 1, 0), 31);
    int4 pi = make_int4(y0c * 32 + x0c, y0c * 32 + x1c, y1c * 32 + x0c,
                        y1c * 32 + x1c);
    float4 ww =
        make_float4((1.f - wx) * (1.f - wy) * ((vx0 && vy0) ? 1.f : 0.f),
                    wx * (1.f - wy) * ((vx1 && vy0) ? 1.f : 0.f),
                    (1.f - wx) * wy * ((vx0 && vy1) ? 1.f : 0.f),
                    wx * wy * ((vx1 && vy1) ? 1.f : 0.f));
    if (s == 0) {
      pxi1[sidx] = pi;
      w1[sidx] = ww;
    } else {
      pxi2[sidx] = pi;
      w2[sidx] = ww;
    }
  }
}

// ---------------------------------------------------------------------------
// m = grid_sample(m_prev) * a on packed planes [b][1024][256]; both branches.
__global__ __launch_bounds__(256) void gs_mul_kernel(
    const unsigned* c0, const unsigned* a0, const int4* pxi0,
    const float4* wg0, unsigned* o0, const unsigned* c1, const unsigned* a1,
    const int4* pxi1, const float4* wg1, unsigned* o1) {
  unsigned flat = blockIdx.x * 256u + threadIdx.x;
  unsigned cg = flat & 31u;
  unsigned px = (flat >> 5) & 1023u;
  unsigned b = (flat >> 15) & 3u;
  unsigned br = flat >> 17;
  const unsigned* c = br ? c1 : c0;
  const unsigned* a = br ? a1 : a0;
  const int4* pxi = br ? pxi1 : pxi0;
  const float4* wg = br ? wg1 : wg0;
  unsigned* o = br ? o1 : o0;
  int4 pi = pxi[b * 1024 + px];
  float4 wv = wg[b * 1024 + px];
  size_t rb = (size_t)b * 1024;
  int co = cg * 8;
  float v[8];
#pragma unroll
  for (int j = 0; j < 8; ++j) v[j] = 0.f;
  const int rows[4] = {pi.x, pi.y, pi.z, pi.w};
  const float wks[4] = {wv.x, wv.y, wv.z, wv.w};
#pragma unroll
  for (int k = 0; k < 4; ++k) {
    const unsigned* p = c + (rb + rows[k]) * 256 + co;
    uint4 u0 = *(const uint4*)p;
    uint4 u1 = *(const uint4*)(p + 4);
    float wk = wks[k];
    v[0] = fmaf(wk, upk(u0.x), v[0]);
    v[1] = fmaf(wk, upk(u0.y), v[1]);
    v[2] = fmaf(wk, upk(u0.z), v[2]);
    v[3] = fmaf(wk, upk(u0.w), v[3]);
    v[4] = fmaf(wk, upk(u1.x), v[4]);
    v[5] = fmaf(wk, upk(u1.y), v[5]);
    v[6] = fmaf(wk, upk(u1.z), v[6]);
    v[7] = fmaf(wk, upk(u1.w), v[7]);
  }
  size_t oo = (rb + px) * 256 + co;
  uint4 au0 = *(const uint4*)(a + oo);
  uint4 au1 = *(const uint4*)(a + oo + 4);
  uint4 r0, r1;
  r0.x = pkpair(v[0] * upk(au0.x));
  r0.y = pkpair(v[1] * upk(au0.y));
  r0.z = pkpair(v[2] * upk(au0.z));
  r0.w = pkpair(v[3] * upk(au0.w));
  r1.x = pkpair(v[4] * upk(au1.x));
  r1.y = pkpair(v[5] * upk(au1.y));
  r1.z = pkpair(v[6] * upk(au1.z));
  r1.w = pkpair(v[7] * upk(au1.w));
  *(uint4*)(o + oo) = r0;
  *(uint4*)(o + oo + 4) = r1;
}

// ---------------------------------------------------------------------------
// merge depthwise 3x3 on concat(ms1,ms2)/ITERS, packed in -> packed out
// [b][1024][512].
__global__ __launch_bounds__(256) void merge_dw_kernel(
    const unsigned* s1, const unsigned* s2, const float* __restrict__ wall,
    unsigned* d) {
  __shared__ float wlds[576];
  int bx = blockIdx.x;
  int pr = bx >> 3, cset = bx & 7;
  int b = blockIdx.y;
  int pc = threadIdx.x & 31, cg = threadIdx.x >> 5;
  for (int i = threadIdx.x; i < 576; i += 256) wlds[i] = wall[cset * 576 + i];
  __syncthreads();
  const unsigned* sp = (cset < 4) ? s1 : s2;
  int csrc = (cset & 3) * 64 + cg * 8;
  float acc[8];
#pragma unroll
  for (int j = 0; j < 8; ++j) acc[j] = 0.f;
#pragma unroll
  for (int dr = -1; dr <= 1; ++dr) {
    int r2 = pr + dr;
    if (r2 < 0 || r2 > 31) continue;
#pragma unroll
    for (int dc = -1; dc <= 1; ++dc) {
      int c2 = pc + dc;
      if (c2 < 0 || c2 > 31) continue;
      const unsigned* p = sp + ((size_t)(b * 1024) + r2 * 32 + c2) * 256 + csrc;
      uint4 u0 = *(const uint4*)p;
      uint4 u1 = *(const uint4*)(p + 4);
      int wi = (dr + 1) * 3 + (dc + 1);
      acc[0] = fmaf(wlds[(cg * 8 + 0) * 9 + wi], upk(u0.x), acc[0]);
      acc[1] = fmaf(wlds[(cg * 8 + 1) * 9 + wi], upk(u0.y), acc[1]);
      acc[2] = fmaf(wlds[(cg * 8 + 2) * 9 + wi], upk(u0.z), acc[2]);
      acc[3] = fmaf(wlds[(cg * 8 + 3) * 9 + wi], upk(u0.w), acc[3]);
      acc[4] = fmaf(wlds[(cg * 8 + 4) * 9 + wi], upk(u1.x), acc[4]);
      acc[5] = fmaf(wlds[(cg * 8 + 5) * 9 + wi], upk(u1.y), acc[5]);
      acc[6] = fmaf(wlds[(cg * 8 + 6) * 9 + wi], upk(u1.z), acc[6]);
      acc[7] = fmaf(wlds[(cg * 8 + 7) * 9 + wi], upk(u1.w), acc[7]);
    }
  }
  size_t oo = ((size_t)(b * 1024) + pr * 32 + pc) * 512 + cset * 64 + cg * 8;
  uint4 r0, r1;
  r0.x = pkpair(acc[0] * 0.1f);
  r0.y = pkpair(acc[1] * 0.1f);
  r0.z = pkpair(acc[2] * 0.1f);
  r0.w = pkpair(acc[3] * 0.1f);
  r1.x = pkpair(acc[4] * 0.1f);
  r1.y = pkpair(acc[5] * 0.1f);
  r1.z = pkpair(acc[6] * 0.1f);
  r1.w = pkpair(acc[7] * 0.1f);
  *(uint4*)(d + oo) = r0;
  *(uint4*)(d + oo + 4) = r1;
}

// ---------------------------------------------------------------------------
// bilinear upsample 32->128, align_corners=True, from fp32 [b][256][1024].
__global__ __launch_bounds__(256) void upsample_kernel(
    const float* __restrict__ mid, float* __restrict__ out) {
  unsigned flat = blockIdx.x * 256u + threadIdx.x;  // f4 units
  unsigned ow4 = flat & 31u;
  unsigned oh = (flat >> 5) & 127u;
  unsigned bc = flat >> 12;  // b*256+c
  const float* pl = mid + (size_t)bc * 1024;
  float rh = oh * (31.f / 127.f);
  float ihf = floorf(rh);
  float wh = rh - ihf;
  int i0 = (int)ihf;
  int i1 = min(i0 + 1, 31);
  const float* r0 = pl + i0 * 32;
  const float* r1 = pl + i1 * 32;
  float4 res;
  float* rp = &res.x;
#pragma unroll
  for (int j = 0; j < 4; j++) {
    unsigned ow = ow4 * 4 + j;
    float rw = ow * (31.f / 127.f);
    float jwf = floorf(rw);
    float ww = rw - jwf;
    int j0 = (int)jwf;
    int j1 = min(j0 + 1, 31);
    float top = r0[j0] * (1.f - ww) + r0[j1] * ww;
    float bot = r1[j0] * (1.f - ww) + r1[j1] * ww;
    rp[j] = top * (1.f - wh) + bot * wh;
  }
  reinterpret_cast<float4*>(out)[flat] = res;
}

// ---------------------------------------------------------------------------
extern "C" void kernel_launch(void* const* d_in, const int* in_sizes, int n_in,
                              void* d_out, int out_size, void* d_ws,
                              size_t ws_size, hipStream_t stream) {
  (void)in_sizes;
  (void)n_in;
  (void)out_size;
  (void)ws_size;
  const float* x = (const float*)d_in[0];
  const float* grads = (const float*)d_in[1];
  const float* bn_gamma = (const float*)d_in[2];
  const float* bn_beta = (const float*)d_in[3];
  const float* bn_mean = (const float*)d_in[4];
  const float* bn_var = (const float*)d_in[5];
  const float* att1_dw = (const float*)d_in[6];
  const float* att1_pw = (const float*)d_in[7];
  const float* att2_dw = (const float*)d_in[8];
  const float* att2_pw = (const float*)d_in[9];
  const float* conv1_w = (const float*)d_in[10];
  const float* conv2_w = (const float*)d_in[11];
  const float* add1_w = (const float*)d_in[12];
  const float* add2_w = (const float*)d_in[13];
  const float* merge_dww = (const float*)d_in[14];
  const float* merge_pww = (const float*)d_in[15];
  float* out = (float*)d_out;

  const size_t MB = 1u << 20;
  uint8_t* base = (uint8_t*)d_ws;
  float* t1 = (float*)base;  // 64 MB scratch (dead after att pw launches)
  uint8_t* P = base + 64 * MB;
  ushort_t* wAtt1 = (ushort_t*)P; P += 262144;
  ushort_t* wAtt2 = (ushort_t*)P; P += 262144;
  ushort_t* wC1 = (ushort_t*)P; P += 262144;
  ushort_t* wC2 = (ushort_t*)P; P += 262144;
  ushort_t* wAdd1 = (ushort_t*)P; P += 524288;
  ushort_t* wAdd2 = (ushort_t*)P; P += 524288;
  ushort_t* wMrg = (ushort_t*)P; P += 524288;
  unsigned* a1p = (unsigned*)P; P += 4 * MB;
  unsigned* a2p = (unsigned*)P; P += 4 * MB;
  unsigned* m1P = (unsigned*)P; P += 4 * MB;
  unsigned* m2P = (unsigned*)P; P += 4 * MB;
  int4* pxi1 = (int4*)P; P += 65536;
  float4* w1g = (float4*)P; P += 65536;
  int4* pxi2 = (int4*)P; P += 65536;
  float4* w2g = (float4*)P; P += 65536;
  // loop region reuses the t1 area, live only after att pw launches
  uint8_t* Q = base;
  unsigned* m1Q = (unsigned*)Q; Q += 4 * MB;
  unsigned* m2Q = (unsigned*)Q; Q += 4 * MB;
  unsigned* s1a = (unsigned*)Q; Q += 4 * MB;
  unsigned* s1b = (unsigned*)Q; Q += 4 * MB;
  unsigned* s2a = (unsigned*)Q; Q += 4 * MB;
  unsigned* s2b = (unsigned*)Q; Q += 4 * MB;
  unsigned* dwm = (unsigned*)Q; Q += 8 * MB;
  float* mid = (float*)Q; Q += 4 * MB;

  wsplit_kernel<<<1792, 256, 0, stream>>>(att1_pw, att2_pw, conv1_w, conv2_w,
                                          add1_w, add2_w, merge_pww, wAtt1,
                                          wAtt2, wC1, wC2, wAdd1, wAdd2, wMrg);
  // m-branch convs straight from x (BN in staging), relu+pool
  pw_mfma_kernel<<<dim3(256, 4, 2), 256, 0, stream>>>(
      x, x, wC1, wC2, m1P, m2P, bn_gamma, bn_beta, bn_mean, bn_var, 1, 1);
  // attention branch 1: dw(BN(x)) -> t1 -> pw+sigmoid+pool
  dw_bn_kernel<<<16384, 256, 0, stream>>>(x, att1_dw, bn_gamma, bn_beta,
                                          bn_mean, bn_var, t1);
  pw_mfma_kernel<<<dim3(256, 4, 1), 256, 0, stream>>>(
      t1, t1, wAtt1, wAtt1, a1p, a1p, bn_gamma, bn_beta, bn_mean, bn_var, 0,
      0);
  // attention branch 2 (reuses t1)
  dw_bn_kernel<<<16384, 256, 0, stream>>>(x, att2_dw, bn_gamma, bn_beta,
                                          bn_mean, bn_var, t1);
  pw_mfma_kernel<<<dim3(256, 4, 1), 256, 0, stream>>>(
      t1, t1, wAtt2, wAtt2, a2p, a2p, bn_gamma, bn_beta, bn_mean, bn_var, 0,
      0);
  grads_pool_kernel<<<16, 256, 0, stream>>>(grads, pxi1, w1g, pxi2, w2g);

  const unsigned *c1 = m1P, *c2 = m2P, *ss1 = m1P, *ss2 = m2P;
  for (int it = 0; it < 10; ++it) {
    unsigned* n1 = (it & 1) ? m1P : m1Q;
    unsigned* n2 = (it & 1) ? m2P : m2Q;
    gs_mul_kernel<<<1024, 256, 0, stream>>>(c1, a1p, pxi1, w1g, n1, c2, a2p,
                                            pxi2, w2g, n2);
    unsigned* so1 = (it & 1) ? s1b : s1a;
    unsigned* so2 = (it & 1) ? s2b : s2a;
    catp_kernel<<<dim3(128, 4, 2), 128, 0, stream>>>(
        ss1, n1, wAdd1, so1, nullptr, ss2, n2, wAdd2, so2, nullptr, 256, 256,
        256, 0);
    c1 = n1;
    c2 = n2;
    ss1 = so1;
    ss2 = so2;
  }
  merge_dw_kernel<<<dim3(256, 4), 256, 0, stream>>>(ss1, ss2, merge_dww, dwm);
  catp_kernel<<<dim3(128, 4, 1), 128, 0, stream>>>(
      dwm, dwm, wMrg, nullptr, mid, dwm, dwm, wMrg, nullptr, mid, 512, 512,
      512, 1);
  upsample_kernel<<<16384, 256, 0, stream>>>(mid, out);
}